// Round 4
// baseline (43.805 us; speedup 1.0000x reference)
//
#include <hip/hip_runtime.h>

// YOLO loss, two-stage reduction.
// R1: same-line atomics serialize -> two-stage plain stores (219->38us).
// R2: 120B-stride loads = line amplification -> LDS tile staging (38->35us).
// R3 lesson: 31.5KB LDS -> only 5 blocks/CU (45% occupancy), latency-bound.
//    Fix: stream pred as coalesced float4 ONCE, classify each float by channel
//    inline (cls-loss + noobj computed during the stream); only the 10 box
//    floats/cell go to LDS (stride 11 = conflict-free). LDS 32KB -> 12.5KB
//    -> 8 blocks/CU (wave cap), ~2x latency hiding.
//
// d_in[0] pred_tensor  f32 [N,S,S,30]
// d_in[1] target_boxes f32 [N,S,S,4]
// d_in[2] target_cls   f32 [N,S,S,20]
// d_in[3] has_object_map bool -> int32 [N,S,S]
// d_out: (total, reg, contain, noobj, cls) f32[5]

namespace {
constexpr float kLCoord = 5.0f;
constexpr float kLNoobj = 0.5f;
constexpr float kInvS   = 1.0f / 14.0f;
constexpr int   kTile   = 256;    // cells per block
constexpr int   kBoxP   = 11;     // padded box stride (gcd(11,32)=1 -> conflict-free)
}

__global__ __launch_bounds__(256) void yolo_partial_kernel(
    const float* __restrict__ pred,
    const float* __restrict__ tbox,
    const float* __restrict__ tcls,
    const int*   __restrict__ mask,
    float* __restrict__ ws,
    int ncells)
{
  __shared__ float lds_box[kTile * kBoxP];   // 11 KB
  __shared__ int   lds_mask[kTile];          // 1 KB
  __shared__ float red[4][4];

  const int tid  = threadIdx.x;
  const int base = blockIdx.x * kTile;
  const int tile_cells = min(kTile, ncells - base);

  float cls_l = 0.f, noobj_l = 0.f, reg_l = 0.f, cont_l = 0.f;

  // ---- Phase A0: mask to LDS (coalesced) ----
  const int m_reg = (tid < tile_cells) ? mask[base + tid] : 0;
  lds_mask[tid] = m_reg;
  __syncthreads();

  // ---- Phase A1: stream pred tile as coalesced float4; classify inline ----
  {
    const float* tcb = tcls + (long)base * 20;
    const float4* src4 = reinterpret_cast<const float4*>(pred + (long)base * 30);
    const int tile_floats = tile_cells * 30;
    const int nf4 = tile_floats >> 2;          // 1920 on a full tile

    for (int i4 = tid; i4 < nf4; i4 += 256) {
      float4 v4 = src4[i4];
      const int f0 = i4 << 2;
      float vv[4] = {v4.x, v4.y, v4.z, v4.w};
#pragma unroll
      for (int k = 0; k < 4; ++k) {
        const int f  = f0 + k;
        const int c  = f / 30;                 // magic-mul div
        const int ch = f - c * 30;
        const float v = vv[k];
        const bool mc = (lds_mask[c] != 0);
        if (ch < 10) {
          lds_box[c * kBoxP + ch] = v;
          if ((ch == 4 || ch == 9) && !mc) noobj_l += v * v;
        } else if (mc) {
          float t = tcb[c * 20 + (ch - 10)];
          float d = v - t;
          cls_l += d * d;
        }
      }
    }
    // scalar tail (partial tile only)
    for (int f = (nf4 << 2) + tid; f < tile_floats; f += 256) {
      const int c  = f / 30;
      const int ch = f - c * 30;
      const float v = pred[(long)base * 30 + f];
      const bool mc = (lds_mask[c] != 0);
      if (ch < 10) {
        lds_box[c * kBoxP + ch] = v;
        if ((ch == 4 || ch == 9) && !mc) noobj_l += v * v;
      } else if (mc) {
        float t = tcb[c * 20 + (ch - 10)];
        float d = v - t;
        cls_l += d * d;
      }
    }
  }
  __syncthreads();

  // ---- Phase B: per-cell box/IoU math (thread t <-> cell base+t) ----
  if (tid < tile_cells && m_reg) {
    const float* lb = lds_box + tid * kBoxP;   // stride 11: conflict-free
    float pb[10];
#pragma unroll
    for (int i = 0; i < 10; ++i) pb[i] = lb[i];

    float4 tb = *(reinterpret_cast<const float4*>(tbox) + (long)(base + tid));
    float tcx = tb.x * kInvS, tcy = tb.y * kInvS;
    float tx1 = tcx - 0.5f * tb.z;
    float ty1 = tcy - 0.5f * tb.w;
    float tx2 = tcx + 0.5f * tb.z;
    float ty2 = tcy + 0.5f * tb.w;
    float ta  = (tx2 - tx1) * (ty2 - ty1);

    float iou0, iou1;
#pragma unroll
    for (int b = 0; b < 2; ++b) {
      float qw = pb[5 * b + 2], qh = pb[5 * b + 3];
      float cx = pb[5 * b + 0] * kInvS, cy = pb[5 * b + 1] * kInvS;
      float px1 = cx - 0.5f * qw, py1 = cy - 0.5f * qh;
      float px2 = cx + 0.5f * qw, py2 = cy + 0.5f * qh;
      float lx = fmaxf(px1, tx1), ly = fmaxf(py1, ty1);
      float rx = fminf(px2, tx2), ry = fminf(py2, ty2);
      float w = fmaxf(rx - lx, 0.f), h = fmaxf(ry - ly, 0.f);
      float inter = w * h;
      float pa = (px2 - px1) * (py2 - py1);
      float v = inter / (pa + ta - inter);
      if (b == 0) iou0 = v; else iou1 = v;
    }

    // jnp.argmax -> first max on tie: box1 only on STRICT greater
    const bool sel = (iou1 > iou0);
    float biou = fmaxf(iou0, iou1);
    float bx = sel ? pb[5] : pb[0];
    float by = sel ? pb[6] : pb[1];
    float bw = sel ? pb[7] : pb[2];
    float bh = sel ? pb[8] : pb[3];
    float bc = sel ? pb[9] : pb[4];

    float dx = bx - tb.x, dy = by - tb.y;
    float dw = sqrtf(bw) - sqrtf(tb.z);
    float dh = sqrtf(bh) - sqrtf(tb.w);
    reg_l = dx * dx + dy * dy + dw * dw + dh * dh;   // *L_COORD in stage 2

    float dc = bc - biou;
    cont_l = dc * dc;
  }

  // ---- wave64 reduction ----
#pragma unroll
  for (int off = 32; off > 0; off >>= 1) {
    cls_l   += __shfl_down(cls_l,   off, 64);
    noobj_l += __shfl_down(noobj_l, off, 64);
    reg_l   += __shfl_down(reg_l,   off, 64);
    cont_l  += __shfl_down(cont_l,  off, 64);
  }

  const int lane = tid & 63;
  const int wid  = tid >> 6;
  if (lane == 0) {
    red[wid][0] = cls_l;
    red[wid][1] = noobj_l;
    red[wid][2] = reg_l;
    red[wid][3] = cont_l;
  }
  __syncthreads();

  if (tid == 0) {
    float c = 0.f, n = 0.f, r = 0.f, t = 0.f;
#pragma unroll
    for (int w = 0; w < 4; ++w) {
      c += red[w][0];
      n += red[w][1];
      r += red[w][2];
      t += red[w][3];
    }
    *(reinterpret_cast<float4*>(ws) + blockIdx.x) = make_float4(c, n, r, t);
  }
}

__global__ __launch_bounds__(256) void yolo_final_kernel(
    const float* __restrict__ ws, int nparts, float* __restrict__ out)
{
  float c = 0.f, n = 0.f, r = 0.f, t = 0.f;
  for (int i = threadIdx.x; i < nparts; i += 256) {
    float4 v = *(reinterpret_cast<const float4*>(ws) + i);
    c += v.x;
    n += v.y;
    r += v.z;
    t += v.w;
  }

#pragma unroll
  for (int off = 32; off > 0; off >>= 1) {
    c += __shfl_down(c, off, 64);
    n += __shfl_down(n, off, 64);
    r += __shfl_down(r, off, 64);
    t += __shfl_down(t, off, 64);
  }

  __shared__ float red[4][4];
  const int lane = threadIdx.x & 63;
  const int wid  = threadIdx.x >> 6;
  if (lane == 0) {
    red[wid][0] = c;
    red[wid][1] = n;
    red[wid][2] = r;
    red[wid][3] = t;
  }
  __syncthreads();

  if (threadIdx.x == 0) {
    float cc = 0.f, nn = 0.f, rr = 0.f, tt = 0.f;
#pragma unroll
    for (int w = 0; w < 4; ++w) {
      cc += red[w][0];
      nn += red[w][1];
      rr += red[w][2];
      tt += red[w][3];
    }
    nn *= kLNoobj;
    rr *= kLCoord;
    out[0] = cc + nn + rr + tt;  // total
    out[1] = rr;                 // reg_loss
    out[2] = tt;                 // contain_loss
    out[3] = nn;                 // no_obj_loss
    out[4] = cc;                 // cls_loss
  }
}

extern "C" void kernel_launch(void* const* d_in, const int* in_sizes, int n_in,
                              void* d_out, int out_size, void* d_ws, size_t ws_size,
                              hipStream_t stream) {
  const float* pred = (const float*)d_in[0];
  const float* tbox = (const float*)d_in[1];
  const float* tcls = (const float*)d_in[2];
  const int*   mask = (const int*)d_in[3];
  float* out = (float*)d_out;
  float* ws  = (float*)d_ws;

  const int ncells = in_sizes[3];              // N*S*S
  const int grid   = (ncells + kTile - 1) / kTile;

  yolo_partial_kernel<<<grid, 256, 0, stream>>>(pred, tbox, tcls, mask, ws, ncells);
  yolo_final_kernel<<<1, 256, 0, stream>>>(ws, grid, out);
}

// Round 5
// 38.063 us; speedup vs baseline: 1.1509x; 1.1509x over previous
//
#include <hip/hip_runtime.h>

// YOLO loss, two-stage reduction.
// R1: same-line atomics serialize -> two-stage plain stores (219->38us).
// R2: 120B-stride loads -> LDS tile staging (38->35us).
// R3: latency-bound; occupancy 45% (LDS 31.5KB). 
// R4 lesson: inline per-float classify (div+branch+scalar tcls) regressed
//    (43.8us) despite 67% occupancy -> occupancy wasn't the binding constraint;
//    instruction/latency serialization is.
// R5: revert to R3 structure + explicit MLP: batch-issue 8 pred float4 loads,
//    tbox, and 5 masked tcls float4 loads into named regs BEFORE the LDS
//    drain + single barrier (T14 async-STAGE). ~14 lines in flight per thread
//    vs ~2 in R3's fused load/ds_write loop.
//
// d_in[0] pred_tensor  f32 [N,S,S,30]
// d_in[1] target_boxes f32 [N,S,S,4]
// d_in[2] target_cls   f32 [N,S,S,20]
// d_in[3] has_object_map bool -> int32 [N,S,S]
// d_out: (total, reg, contain, noobj, cls) f32[5]

namespace {
constexpr float kLCoord = 5.0f;
constexpr float kLNoobj = 0.5f;
constexpr float kInvS   = 1.0f / 14.0f;
constexpr int   kTile   = 256;    // cells per block
}

__global__ __launch_bounds__(256) void yolo_partial_kernel(
    const float* __restrict__ pred,
    const float* __restrict__ tbox,
    const float* __restrict__ tcls,
    const int*   __restrict__ mask,
    float* __restrict__ ws,
    int ncells)
{
  __shared__ float lds_pred[kTile * 30];   // 30 KB linear, cell-major
  __shared__ int   lds_mask[kTile];        // 1 KB
  __shared__ float red[4][4];

  const int tid  = threadIdx.x;
  const int base = blockIdx.x * kTile;
  const int tile_cells = min(kTile, ncells - base);
  const int nfl = tile_cells * 30;
  const int nf4 = nfl >> 2;            // 1920 on a full tile
  const int nc4 = tile_cells * 5;      // tcls float4 count (1280 full)

  float cls_l = 0.f, noobj_l = 0.f, reg_l = 0.f, cont_l = 0.f;

  // ---- mask (own cell) ----
  const int m_reg = (tid < tile_cells) ? mask[base + tid] : 0;
  lds_mask[tid] = m_reg;

  // ---- Phase A1: batch-issue 8 coalesced pred float4 loads (named regs) ----
  const float4* src4 = reinterpret_cast<const float4*>(pred + (long)base * 30);
  float4 r0, r1, r2, r3, r4, r5, r6, r7;
  if (tid            < nf4) r0 = src4[tid];
  if (tid +  1 * 256 < nf4) r1 = src4[tid + 1 * 256];
  if (tid +  2 * 256 < nf4) r2 = src4[tid + 2 * 256];
  if (tid +  3 * 256 < nf4) r3 = src4[tid + 3 * 256];
  if (tid +  4 * 256 < nf4) r4 = src4[tid + 4 * 256];
  if (tid +  5 * 256 < nf4) r5 = src4[tid + 5 * 256];
  if (tid +  6 * 256 < nf4) r6 = src4[tid + 6 * 256];
  if (tid +  7 * 256 < nf4) r7 = src4[tid + 7 * 256];

  // ---- tbox early (only needed for masked cells) ----
  float4 tb = make_float4(0.f, 0.f, 0.f, 0.f);
  if (tid < tile_cells && m_reg)
    tb = *(reinterpret_cast<const float4*>(tbox) + (long)(base + tid));

  // ---- Phase A2: prefetch tcls float4s for phase C (mask re-read from global,
  //      L1/L2-hot; avoids a barrier dependency on lds_mask) ----
  const float4* tc4p = reinterpret_cast<const float4*>(tcls) + (long)base * 5;
  float4 t0 = make_float4(0.f,0.f,0.f,0.f), t1 = t0, t2 = t0, t3 = t0, t4 = t0;
#define LOAD_TC(K, TK)                                              \
  { const int i = tid + (K << 8);                                   \
    if (i < nc4) { const int cl = i / 5;                            \
      if (mask[base + cl]) TK = tc4p[i]; } }
  LOAD_TC(0, t0) LOAD_TC(1, t1) LOAD_TC(2, t2) LOAD_TC(3, t3) LOAD_TC(4, t4)
#undef LOAD_TC

  // ---- Phase A3: drain pred regs into LDS ----
  {
    float4* dst4 = reinterpret_cast<float4*>(lds_pred);
    if (tid            < nf4) dst4[tid]           = r0;
    if (tid +  1 * 256 < nf4) dst4[tid + 1 * 256] = r1;
    if (tid +  2 * 256 < nf4) dst4[tid + 2 * 256] = r2;
    if (tid +  3 * 256 < nf4) dst4[tid + 3 * 256] = r3;
    if (tid +  4 * 256 < nf4) dst4[tid + 4 * 256] = r4;
    if (tid +  5 * 256 < nf4) dst4[tid + 5 * 256] = r5;
    if (tid +  6 * 256 < nf4) dst4[tid + 6 * 256] = r6;
    if (tid +  7 * 256 < nf4) dst4[tid + 7 * 256] = r7;
    // scalar tail (partial tile only)
    for (int f = (nf4 << 2) + tid; f < nfl; f += 256)
      lds_pred[f] = pred[(long)base * 30 + f];
  }
  __syncthreads();   // mask + pred tile visible

  // ---- Phase B: per-cell box/IoU math (thread t <-> cell base+t) ----
  if (tid < tile_cells) {
    const float2* lp2 = reinterpret_cast<const float2*>(lds_pred + tid * 30);
    float pb[10];
#pragma unroll
    for (int i = 0; i < 5; ++i) {
      float2 v = lp2[i];
      pb[2 * i]     = v.x;
      pb[2 * i + 1] = v.y;
    }

    if (!m_reg) {
      noobj_l = pb[4] * pb[4] + pb[9] * pb[9];
    } else {
      float tcx = tb.x * kInvS, tcy = tb.y * kInvS;
      float tx1 = tcx - 0.5f * tb.z;
      float ty1 = tcy - 0.5f * tb.w;
      float tx2 = tcx + 0.5f * tb.z;
      float ty2 = tcy + 0.5f * tb.w;
      float ta  = (tx2 - tx1) * (ty2 - ty1);

      float iou0, iou1;
#pragma unroll
      for (int b = 0; b < 2; ++b) {
        float qw = pb[5 * b + 2], qh = pb[5 * b + 3];
        float cx = pb[5 * b + 0] * kInvS, cy = pb[5 * b + 1] * kInvS;
        float px1 = cx - 0.5f * qw, py1 = cy - 0.5f * qh;
        float px2 = cx + 0.5f * qw, py2 = cy + 0.5f * qh;
        float lx = fmaxf(px1, tx1), ly = fmaxf(py1, ty1);
        float rx = fminf(px2, tx2), ry = fminf(py2, ty2);
        float w = fmaxf(rx - lx, 0.f), h = fmaxf(ry - ly, 0.f);
        float inter = w * h;
        float pa = (px2 - px1) * (py2 - py1);
        float v = inter / (pa + ta - inter);
        if (b == 0) iou0 = v; else iou1 = v;
      }

      // jnp.argmax -> first max on tie: box1 only on STRICT greater
      const bool sel = (iou1 > iou0);
      float biou = fmaxf(iou0, iou1);
      float bx = sel ? pb[5] : pb[0];
      float by = sel ? pb[6] : pb[1];
      float bw = sel ? pb[7] : pb[2];
      float bh = sel ? pb[8] : pb[3];
      float bc = sel ? pb[9] : pb[4];

      float dx = bx - tb.x, dy = by - tb.y;
      float dw = sqrtf(bw) - sqrtf(tb.z);
      float dh = sqrtf(bh) - sqrtf(tb.w);
      reg_l = dx * dx + dy * dy + dw * dw + dh * dh;   // *L_COORD in stage 2

      float dc = bc - biou;
      cont_l = dc * dc;
    }
  }

  // ---- Phase C: cls loss, element-parallel; tcls already in regs ----
#define PHASE_C(K, TK)                                                        \
  { const int i = tid + (K << 8);                                             \
    if (i < nc4) { const int cl = i / 5;                                      \
      if (lds_mask[cl]) {                                                     \
        const float2* lp2 = reinterpret_cast<const float2*>(                  \
            lds_pred + cl * 30 + 10 + ((i - cl * 5) << 2));                   \
        float2 a0 = lp2[0], a1 = lp2[1];                                      \
        float c0 = a0.x - TK.x;                                               \
        float c1 = a0.y - TK.y;                                               \
        float c2 = a1.x - TK.z;                                               \
        float c3 = a1.y - TK.w;                                               \
        cls_l += c0 * c0 + c1 * c1 + c2 * c2 + c3 * c3; } } }
  PHASE_C(0, t0) PHASE_C(1, t1) PHASE_C(2, t2) PHASE_C(3, t3) PHASE_C(4, t4)
#undef PHASE_C

  // ---- wave64 reduction ----
#pragma unroll
  for (int off = 32; off > 0; off >>= 1) {
    cls_l   += __shfl_down(cls_l,   off, 64);
    noobj_l += __shfl_down(noobj_l, off, 64);
    reg_l   += __shfl_down(reg_l,   off, 64);
    cont_l  += __shfl_down(cont_l,  off, 64);
  }

  const int lane = tid & 63;
  const int wid  = tid >> 6;
  if (lane == 0) {
    red[wid][0] = cls_l;
    red[wid][1] = noobj_l;
    red[wid][2] = reg_l;
    red[wid][3] = cont_l;
  }
  __syncthreads();

  if (tid == 0) {
    float c = 0.f, n = 0.f, r = 0.f, t = 0.f;
#pragma unroll
    for (int w = 0; w < 4; ++w) {
      c += red[w][0];
      n += red[w][1];
      r += red[w][2];
      t += red[w][3];
    }
    *(reinterpret_cast<float4*>(ws) + blockIdx.x) = make_float4(c, n, r, t);
  }
}

__global__ __launch_bounds__(256) void yolo_final_kernel(
    const float* __restrict__ ws, int nparts, float* __restrict__ out)
{
  float c = 0.f, n = 0.f, r = 0.f, t = 0.f;
  for (int i = threadIdx.x; i < nparts; i += 256) {
    float4 v = *(reinterpret_cast<const float4*>(ws) + i);
    c += v.x;
    n += v.y;
    r += v.z;
    t += v.w;
  }

#pragma unroll
  for (int off = 32; off > 0; off >>= 1) {
    c += __shfl_down(c, off, 64);
    n += __shfl_down(n, off, 64);
    r += __shfl_down(r, off, 64);
    t += __shfl_down(t, off, 64);
  }

  __shared__ float red[4][4];
  const int lane = threadIdx.x & 63;
  const int wid  = threadIdx.x >> 6;
  if (lane == 0) {
    red[wid][0] = c;
    red[wid][1] = n;
    red[wid][2] = r;
    red[wid][3] = t;
  }
  __syncthreads();

  if (threadIdx.x == 0) {
    float cc = 0.f, nn = 0.f, rr = 0.f, tt = 0.f;
#pragma unroll
    for (int w = 0; w < 4; ++w) {
      cc += red[w][0];
      nn += red[w][1];
      rr += red[w][2];
      tt += red[w][3];
    }
    nn *= kLNoobj;
    rr *= kLCoord;
    out[0] = cc + nn + rr + tt;  // total
    out[1] = rr;                 // reg_loss
    out[2] = tt;                 // contain_loss
    out[3] = nn;                 // no_obj_loss
    out[4] = cc;                 // cls_loss
  }
}

extern "C" void kernel_launch(void* const* d_in, const int* in_sizes, int n_in,
                              void* d_out, int out_size, void* d_ws, size_t ws_size,
                              hipStream_t stream) {
  const float* pred = (const float*)d_in[0];
  const float* tbox = (const float*)d_in[1];
  const float* tcls = (const float*)d_in[2];
  const int*   mask = (const int*)d_in[3];
  float* out = (float*)d_out;
  float* ws  = (float*)d_ws;

  const int ncells = in_sizes[3];              // N*S*S
  const int grid   = (ncells + kTile - 1) / kTile;

  yolo_partial_kernel<<<grid, 256, 0, stream>>>(pred, tbox, tcls, mask, ws, ncells);
  yolo_final_kernel<<<1, 256, 0, stream>>>(ws, grid, out);
}